// Round 1
// baseline (1759.907 us; speedup 1.0000x reference)
//
#include <hip/hip_runtime.h>
#include <cstdint>
#include <cstddef>

// GAT 2-layer (N=8192, D=256, fp32), flash-style softmax, rank-1 scores.
// e[i][j] = leaky(s[i]+d[j]) masked by adj; attn = softmax rows; out = relu(attn@Wh).
// Workspace layout (needs ~32.2 MB):
//   [0,8MB)    Wh          8192x256 f32
//   [8,16MB)   bits        8192x128 u64 (packed adj, built in layer-1 stats)
//   [16,32MB)  pout        2 x 8192x256 f32 (j-half partial sums)
//   [32MB+..)  s, dd, m, rl  4 x 8192 f32
// Layer-1 output h is written into d_out (reused as layer-2 input).

#define ALPHA 0.2f
#define NN 8192
#define DD 256

// ---------------- GEMM: C[M x 256] = A[M x 256] @ B[256 x 256] ----------------
__global__ __launch_bounds__(256) void gemm_k256(const float* __restrict__ A,
                                                 const float* __restrict__ B,
                                                 float* __restrict__ C) {
    __shared__ __align__(16) float At[32][68];   // A^T tile [k][r], padded, 16B rows
    __shared__ float4 Bs[32][64];                // B tile [k][c4]
    const int t = threadIdx.x;
    const int m0 = blockIdx.x * 64;
    const int r0 = (t >> 5) * 8;
    const int c0 = (t & 31) * 8;
    float acc[8][8];
#pragma unroll
    for (int i = 0; i < 8; i++)
#pragma unroll
        for (int j = 0; j < 8; j++) acc[i][j] = 0.f;

    for (int k0 = 0; k0 < 256; k0 += 32) {
#pragma unroll
        for (int l = 0; l < 2; l++) {
            int fi = t + 256 * l;          // 0..511
            int row = fi >> 3;             // 0..63
            int kq = fi & 7;               // float4 idx in 32 k's
            float4 v = *(const float4*)(A + (size_t)(m0 + row) * DD + k0 + kq * 4);
            At[kq * 4 + 0][row] = v.x;
            At[kq * 4 + 1][row] = v.y;
            At[kq * 4 + 2][row] = v.z;
            At[kq * 4 + 3][row] = v.w;
        }
#pragma unroll
        for (int l = 0; l < 8; l++) {
            int fi = t + 256 * l;          // 0..2047
            int br = fi >> 6;
            int bc = fi & 63;
            Bs[br][bc] = *(const float4*)(B + (size_t)(k0 + br) * DD + bc * 4);
        }
        __syncthreads();
#pragma unroll
        for (int k = 0; k < 32; k++) {
            const float4* ap = (const float4*)&At[k][r0];
            float4 a0 = ap[0], a1 = ap[1];
            float4 b0 = Bs[k][c0 >> 2], b1 = Bs[k][(c0 >> 2) + 1];
            float a[8] = {a0.x, a0.y, a0.z, a0.w, a1.x, a1.y, a1.z, a1.w};
            float b[8] = {b0.x, b0.y, b0.z, b0.w, b1.x, b1.y, b1.z, b1.w};
#pragma unroll
            for (int i = 0; i < 8; i++)
#pragma unroll
                for (int j = 0; j < 8; j++) acc[i][j] += a[i] * b[j];
        }
        __syncthreads();
    }
#pragma unroll
    for (int i = 0; i < 8; i++) {
        float4 v0 = {acc[i][0], acc[i][1], acc[i][2], acc[i][3]};
        float4 v1 = {acc[i][4], acc[i][5], acc[i][6], acc[i][7]};
        *(float4*)(C + (size_t)(m0 + r0 + i) * DD + c0) = v0;
        *(float4*)(C + (size_t)(m0 + r0 + i) * DD + c0 + 4) = v1;
    }
}

// ------------- s[i] = Wh[i].a_src ; dd[i] = Wh[i].a_dst (1 wave/row) -------------
__global__ __launch_bounds__(256) void rowdots(const float* __restrict__ Wh,
                                               const float* __restrict__ a_src,
                                               const float* __restrict__ a_dst,
                                               float* __restrict__ s,
                                               float* __restrict__ dd) {
    int wave = threadIdx.x >> 6;
    int lane = threadIdx.x & 63;
    int row = blockIdx.x * 4 + wave;
    float4 w = *(const float4*)(Wh + (size_t)row * DD + lane * 4);
    float4 as = *(const float4*)(a_src + lane * 4);
    float4 ad = *(const float4*)(a_dst + lane * 4);
    float ss = w.x * as.x + w.y * as.y + w.z * as.z + w.w * as.w;
    float sd = w.x * ad.x + w.y * ad.y + w.z * ad.z + w.w * ad.w;
#pragma unroll
    for (int off = 32; off; off >>= 1) {
        ss += __shfl_down(ss, off);
        sd += __shfl_down(sd, off);
    }
    if (lane == 0) { s[row] = ss; dd[row] = sd; }
}

// -------- per-row softmax stats: m (max) and 1/l (sum of exp); packs bitmask --------
// mode 0: read adj int32, write bits. mode 1: read bits.
__global__ __launch_bounds__(256) void rowstats(const int* __restrict__ adj,
                                                const uint64_t* __restrict__ bits_in,
                                                uint64_t* __restrict__ bits_out,
                                                const float* __restrict__ s,
                                                const float* __restrict__ dd,
                                                float* __restrict__ m_out,
                                                float* __restrict__ rl_out,
                                                int mode) {
    __shared__ uint64_t masks[128];
    __shared__ float wmax[4];
    __shared__ float wsum[4];
    const int i = blockIdx.x;
    const int t = threadIdx.x;
    const int wave = t >> 6, lane = t & 63;
    const float si = s[i];
    float mx = -3.0e38f;

    if (mode == 0) {
        for (int it = 0; it < 32; it++) {
            int j = it * 256 + t;
            int a = adj[(size_t)i * NN + j];
            unsigned long long mk = __ballot(a != 0);
            if (lane == 0) masks[it * 4 + wave] = mk;
            if (a != 0) {
                float e = si + dd[j];
                e = e >= 0.f ? e : ALPHA * e;
                mx = fmaxf(mx, e);
            }
        }
    } else {
        for (int it = 0; it < 32; it++) {
            int j = it * 256 + t;
            int widx = it * 4 + wave;
            uint64_t mk = bits_in[(size_t)i * 128 + widx];
            if (lane == 0) masks[widx] = mk;
            if ((mk >> lane) & 1ull) {
                float e = si + dd[j];
                e = e >= 0.f ? e : ALPHA * e;
                mx = fmaxf(mx, e);
            }
        }
    }
#pragma unroll
    for (int off = 32; off; off >>= 1) mx = fmaxf(mx, __shfl_down(mx, off));
    if (lane == 0) wmax[wave] = mx;
    __syncthreads();
    const float mrow = fmaxf(fmaxf(wmax[0], wmax[1]), fmaxf(wmax[2], wmax[3]));

    float sm = 0.f;
    for (int it = 0; it < 32; it++) {
        int j = it * 256 + t;
        uint64_t mk = masks[it * 4 + wave];
        if ((mk >> lane) & 1ull) {
            float e = si + dd[j];
            e = e >= 0.f ? e : ALPHA * e;
            sm += __expf(e - mrow);
        }
    }
#pragma unroll
    for (int off = 32; off; off >>= 1) sm += __shfl_down(sm, off);
    if (lane == 0) wsum[wave] = sm;
    __syncthreads();
    if (t == 0) {
        float l = wsum[0] + wsum[1] + wsum[2] + wsum[3];
        m_out[i] = mrow;
        rl_out[i] = 1.0f / l;   // every row has neighbors for this input (p=0.5, N=8192)
    }
    if (mode == 0) {
        if (t < 128) bits_out[(size_t)i * 128 + t] = masks[t];
    }
}

// -------- PV: pout[half][i][:] = sum_j p_ij * Wh[j][:], p from (s,dd,m,rl,bits) --------
// 256 blocks: 128 i-tiles (64 rows) x 2 j-halves (4096 each). 8x8 fp32 microtiles.
__global__ __launch_bounds__(256) void pv(const float* __restrict__ Wh,
                                          const uint64_t* __restrict__ bits,
                                          const float* __restrict__ s,
                                          const float* __restrict__ dd,
                                          const float* __restrict__ m,
                                          const float* __restrict__ rl,
                                          float* __restrict__ pout) {
    __shared__ float4 Ws[32][64];                 // Wh tile [k][c4] (32 KB)
    __shared__ __align__(16) float Pt[32][68];    // P^T tile [jj][r], 16B rows
    const int t = threadIdx.x;
    const int ib = blockIdx.x >> 1;
    const int half = blockIdx.x & 1;              // even/odd -> different XCD sets
    const int i0 = ib * 64;
    const int r0 = (t >> 5) * 8, c0 = (t & 31) * 8;

    // P-gen mapping: fixed row pr = t>>2, jj0 = (t&3)*8 -> per-row params hoisted
    const int pr = t >> 2;
    const int jj0 = (t & 3) * 8;
    const float si = s[i0 + pr];
    const float mi = m[i0 + pr];
    const float rli = rl[i0 + pr];
    const uint64_t* brow = bits + (size_t)(i0 + pr) * 128;

    float acc[8][8];
#pragma unroll
    for (int i = 0; i < 8; i++)
#pragma unroll
        for (int j = 0; j < 8; j++) acc[i][j] = 0.f;

    for (int jt = 0; jt < 128; jt++) {
        const int j0 = half * 4096 + jt * 32;
        __syncthreads();
        // P^T tile: 64 rows x 32 j
        {
            uint64_t wbits = brow[j0 >> 6];
            int bbase = (j0 & 63) + jj0;
            float4 d0 = *(const float4*)(dd + j0 + jj0);
            float4 d1 = *(const float4*)(dd + j0 + jj0 + 4);
            float dv[8] = {d0.x, d0.y, d0.z, d0.w, d1.x, d1.y, d1.z, d1.w};
#pragma unroll
            for (int u = 0; u < 8; u++) {
                float e = si + dv[u];
                e = e >= 0.f ? e : ALPHA * e;
                float p = ((wbits >> (bbase + u)) & 1ull) ? __expf(e - mi) * rli : 0.f;
                Pt[jj0 + u][pr] = p;
            }
        }
        // Wh tile: 32 x 256
#pragma unroll
        for (int l = 0; l < 8; l++) {
            int fi = l * 256 + t;
            int wr = fi >> 6, wc = fi & 63;
            Ws[wr][wc] = *(const float4*)(Wh + (size_t)(j0 + wr) * DD + wc * 4);
        }
        __syncthreads();
#pragma unroll
        for (int k = 0; k < 32; k++) {
            const float4* pp = (const float4*)&Pt[k][r0];
            float4 a0 = pp[0], a1 = pp[1];
            float4 b0 = Ws[k][c0 >> 2], b1 = Ws[k][(c0 >> 2) + 1];
            float a[8] = {a0.x, a0.y, a0.z, a0.w, a1.x, a1.y, a1.z, a1.w};
            float b[8] = {b0.x, b0.y, b0.z, b0.w, b1.x, b1.y, b1.z, b1.w};
#pragma unroll
            for (int i2 = 0; i2 < 8; i2++)
#pragma unroll
                for (int j2 = 0; j2 < 8; j2++) acc[i2][j2] += a[i2] * b[j2];
        }
    }
    float* outp = pout + (size_t)half * NN * DD;
#pragma unroll
    for (int i2 = 0; i2 < 8; i2++) {
        float4 v0 = {acc[i2][0], acc[i2][1], acc[i2][2], acc[i2][3]};
        float4 v1 = {acc[i2][4], acc[i2][5], acc[i2][6], acc[i2][7]};
        *(float4*)(outp + (size_t)(i0 + r0 + i2) * DD + c0) = v0;
        *(float4*)(outp + (size_t)(i0 + r0 + i2) * DD + c0 + 4) = v1;
    }
}

// -------- out = relu(pa + pb) --------
__global__ __launch_bounds__(256) void combine_relu(const float* __restrict__ pa,
                                                    const float* __restrict__ pb,
                                                    float* __restrict__ out) {
    int idx = blockIdx.x * 256 + threadIdx.x;
    float4 a = ((const float4*)pa)[idx];
    float4 b = ((const float4*)pb)[idx];
    float4 o;
    o.x = fmaxf(a.x + b.x, 0.f);
    o.y = fmaxf(a.y + b.y, 0.f);
    o.z = fmaxf(a.z + b.z, 0.f);
    o.w = fmaxf(a.w + b.w, 0.f);
    ((float4*)out)[idx] = o;
}

extern "C" void kernel_launch(void* const* d_in, const int* in_sizes, int n_in,
                              void* d_out, int out_size, void* d_ws, size_t ws_size,
                              hipStream_t stream) {
    const float* x   = (const float*)d_in[0];
    const int* adj   = (const int*)d_in[1];
    const float* W1  = (const float*)d_in[2];
    const float* a1s = (const float*)d_in[3];
    const float* a1d = (const float*)d_in[4];
    const float* W2  = (const float*)d_in[5];
    const float* a2s = (const float*)d_in[6];
    const float* a2d = (const float*)d_in[7];
    float* out = (float*)d_out;

    char* ws = (char*)d_ws;
    const size_t MB = 1024ull * 1024ull;
    float*    Wh   = (float*)(ws);                 // 8 MB
    uint64_t* bits = (uint64_t*)(ws + 8 * MB);     // 8 MB
    float*    pout = (float*)(ws + 16 * MB);       // 16 MB (2 halves)
    float*    sArr = (float*)(ws + 32 * MB);       // 32 KB
    float*    ddA  = (float*)(ws + 32 * MB + 32 * 1024);
    float*    mArr = (float*)(ws + 32 * MB + 64 * 1024);
    float*    rlA  = (float*)(ws + 32 * MB + 96 * 1024);
    const size_t HALF = (size_t)NN * DD;           // 2097152 floats

    // ---------------- Layer 1 ----------------
    gemm_k256<<<dim3(128), dim3(256), 0, stream>>>(x, W1, Wh);
    rowdots<<<dim3(2048), dim3(256), 0, stream>>>(Wh, a1s, a1d, sArr, ddA);
    rowstats<<<dim3(NN), dim3(256), 0, stream>>>(adj, nullptr, bits, sArr, ddA, mArr, rlA, 0);
    pv<<<dim3(256), dim3(256), 0, stream>>>(Wh, bits, sArr, ddA, mArr, rlA, pout);
    combine_relu<<<dim3(2048), dim3(256), 0, stream>>>(pout, pout + HALF, out); // h -> d_out

    // ---------------- Layer 2 ----------------
    gemm_k256<<<dim3(128), dim3(256), 0, stream>>>(out, W2, Wh);
    rowdots<<<dim3(2048), dim3(256), 0, stream>>>(Wh, a2s, a2d, sArr, ddA);
    rowstats<<<dim3(NN), dim3(256), 0, stream>>>(nullptr, bits, nullptr, sArr, ddA, mArr, rlA, 1);
    pv<<<dim3(256), dim3(256), 0, stream>>>(Wh, bits, sArr, ddA, mArr, rlA, pout);
    combine_relu<<<dim3(2048), dim3(256), 0, stream>>>(pout, pout + HALF, out);
}

// Round 2
// 1283.957 us; speedup vs baseline: 1.3707x; 1.3707x over previous
//
#include <hip/hip_runtime.h>
#include <cstdint>
#include <cstddef>

// GAT 2-layer (N=8192, D=256), flash softmax with rank-1 scores, bf16 MFMA PV.
// p_ij = adj_ij ? softmax(leaky(s_i+d_j)) : 0, factored as
//   p = mask * (s_i+d_j>=0 ? E'_i*F_j : G'_i*H_j)
//   E'=rl*exp(s-m), G'=rl*exp(a*s-m)  (per row i);  F=exp(d), H=exp(a*d) (per col j)
// PV uses mfma_f32_16x16x32_bf16 with P generated straight into A-fragment order
// and Wh^T (bf16) staged into B-fragment order via global_load_lds(16B).
// ws (~21 MB): Wh f32 @0 (8MB) | bits @8MB (8MB) | 8 small arrays @16MB (256KB)
//              | WhbT bf16 @17MB (4MB)

#define ALPHA 0.2f
#define NN 8192
#define DD 256

typedef __attribute__((ext_vector_type(8))) short short8;
typedef __attribute__((ext_vector_type(4))) float f32x4;

__device__ __forceinline__ unsigned bf16rne(float x) {
    union { float f; unsigned u; } c; c.f = x;
    return (c.u + 0x7fffu + ((c.u >> 16) & 1u)) >> 16;
}

// ---------------- GEMM: C[8192 x 256] = A @ B[256 x 256], fp32 ----------------
// M-tile 32 (256 blocks = 1/CU full chip); split-column B reads (conflict-free).
__global__ __launch_bounds__(256) void gemm_k256(const float* __restrict__ A,
                                                 const float* __restrict__ B,
                                                 float* __restrict__ C) {
    __shared__ __align__(16) float At[32][36];   // A^T [k][r], 144B rows (16B mult)
    __shared__ __align__(16) float4 Bs[32][64];
    const int t = threadIdx.x;
    const int m0 = blockIdx.x * 32;
    const int r0 = (t >> 5) * 4;
    const int cl = t & 31;                       // float4 col idx; high half = +32
    float acc[4][8];
#pragma unroll
    for (int i = 0; i < 4; i++)
#pragma unroll
        for (int j = 0; j < 8; j++) acc[i][j] = 0.f;

    for (int k0 = 0; k0 < DD; k0 += 32) {
        {
            int row = t >> 3, kq = t & 7;
            float4 v = *(const float4*)(A + (size_t)(m0 + row) * DD + k0 + kq * 4);
            At[kq * 4 + 0][row] = v.x; At[kq * 4 + 1][row] = v.y;
            At[kq * 4 + 2][row] = v.z; At[kq * 4 + 3][row] = v.w;
        }
#pragma unroll
        for (int l2 = 0; l2 < 8; l2++) {
            int fi = l2 * 256 + t;
            Bs[fi >> 6][fi & 63] =
                *(const float4*)(B + (size_t)(k0 + (fi >> 6)) * DD + (fi & 63) * 4);
        }
        __syncthreads();
#pragma unroll
        for (int k = 0; k < 32; k++) {
            float4 a0 = *(const float4*)&At[k][r0];
            float4 b0 = Bs[k][cl], b1 = Bs[k][cl + 32];
            float av[4] = {a0.x, a0.y, a0.z, a0.w};
            float bv[8] = {b0.x, b0.y, b0.z, b0.w, b1.x, b1.y, b1.z, b1.w};
#pragma unroll
            for (int i = 0; i < 4; i++)
#pragma unroll
                for (int j = 0; j < 8; j++) acc[i][j] += av[i] * bv[j];
        }
        __syncthreads();
    }
#pragma unroll
    for (int i = 0; i < 4; i++) {
        float4 v0 = {acc[i][0], acc[i][1], acc[i][2], acc[i][3]};
        float4 v1 = {acc[i][4], acc[i][5], acc[i][6], acc[i][7]};
        *(float4*)(C + (size_t)(m0 + r0 + i) * DD + cl * 4) = v0;
        *(float4*)(C + (size_t)(m0 + r0 + i) * DD + 128 + cl * 4) = v1;
    }
}

// ------- s[i]=Wh[i].a_src; d[i]=Wh[i].a_dst; F=exp(d); H=exp(a*d) (1 wave/row) -------
__global__ __launch_bounds__(256) void rowdots(const float* __restrict__ Wh,
                                               const float* __restrict__ a_src,
                                               const float* __restrict__ a_dst,
                                               float* __restrict__ s,
                                               float* __restrict__ dd,
                                               float* __restrict__ Fv,
                                               float* __restrict__ Hv) {
    int wave = threadIdx.x >> 6;
    int lane = threadIdx.x & 63;
    int row = blockIdx.x * 4 + wave;
    float4 w = *(const float4*)(Wh + (size_t)row * DD + lane * 4);
    float4 as = *(const float4*)(a_src + lane * 4);
    float4 ad = *(const float4*)(a_dst + lane * 4);
    float ss = w.x * as.x + w.y * as.y + w.z * as.z + w.w * as.w;
    float sd = w.x * ad.x + w.y * ad.y + w.z * ad.z + w.w * ad.w;
#pragma unroll
    for (int off = 32; off; off >>= 1) {
        ss += __shfl_down(ss, off);
        sd += __shfl_down(sd, off);
    }
    if (lane == 0) {
        s[row] = ss; dd[row] = sd;
        Fv[row] = __expf(sd); Hv[row] = __expf(ALPHA * sd);
    }
}

// ------ per-row m, rl=1/l; E'=rl*exp(s-m), G'=rl*exp(a*s-m); packs bitmask (mode 0) ------
__global__ __launch_bounds__(256) void rowstats(const int* __restrict__ adj,
                                                const uint64_t* __restrict__ bits_in,
                                                uint64_t* __restrict__ bits_out,
                                                const float* __restrict__ s,
                                                const float* __restrict__ dd,
                                                float* __restrict__ Ep,
                                                float* __restrict__ Gp,
                                                int mode) {
    __shared__ uint64_t masks[128];
    __shared__ float wmax[4];
    __shared__ float wsum[4];
    const int i = blockIdx.x;
    const int t = threadIdx.x;
    const int wave = t >> 6, lane = t & 63;
    const float si = s[i];
    float mx = -3.0e38f;

    if (mode == 0) {
        for (int it = 0; it < 32; it++) {
            int j = it * 256 + t;
            int a = adj[(size_t)i * NN + j];
            unsigned long long mk = __ballot(a != 0);
            if (lane == 0) masks[it * 4 + wave] = mk;
            if (a != 0) {
                float e = si + dd[j];
                e = e >= 0.f ? e : ALPHA * e;
                mx = fmaxf(mx, e);
            }
        }
    } else {
        for (int it = 0; it < 32; it++) {
            int j = it * 256 + t;
            int widx = it * 4 + wave;
            uint64_t mk = bits_in[(size_t)i * 128 + widx];
            if (lane == 0) masks[widx] = mk;
            if ((mk >> lane) & 1ull) {
                float e = si + dd[j];
                e = e >= 0.f ? e : ALPHA * e;
                mx = fmaxf(mx, e);
            }
        }
    }
#pragma unroll
    for (int off = 32; off; off >>= 1) mx = fmaxf(mx, __shfl_down(mx, off));
    if (lane == 0) wmax[wave] = mx;
    __syncthreads();
    const float mrow = fmaxf(fmaxf(wmax[0], wmax[1]), fmaxf(wmax[2], wmax[3]));

    float sm = 0.f;
    for (int it = 0; it < 32; it++) {
        int j = it * 256 + t;
        uint64_t mk = masks[it * 4 + wave];
        if ((mk >> lane) & 1ull) {
            float e = si + dd[j];
            e = e >= 0.f ? e : ALPHA * e;
            sm += __expf(e - mrow);
        }
    }
#pragma unroll
    for (int off = 32; off; off >>= 1) sm += __shfl_down(sm, off);
    if (lane == 0) wsum[wave] = sm;
    __syncthreads();
    if (t == 0) {
        float rl = 1.0f / (wsum[0] + wsum[1] + wsum[2] + wsum[3]);
        Ep[i] = rl * __expf(si - mrow);
        Gp[i] = rl * __expf(ALPHA * si - mrow);
    }
    if (mode == 0) {
        if (t < 128) bits_out[(size_t)i * 128 + t] = masks[t];
    }
}

// ---------------- Wh f32 [8192][256] -> WhbT bf16 [256][8192] ----------------
__global__ __launch_bounds__(256) void transp_bf16(const float* __restrict__ Wh,
                                                   unsigned short* __restrict__ WhbT) {
    __shared__ float tile[64][65];
    const int t = threadIdx.x;
    const int j0 = (int)(blockIdx.x >> 2) * 64;
    const int cc0 = (int)(blockIdx.x & 3) * 64;
#pragma unroll
    for (int l2 = 0; l2 < 4; l2++) {
        int fi = l2 * 256 + t;
        int row = fi >> 4, c4 = (fi & 15) * 4;
        float4 v = *(const float4*)(Wh + (size_t)(j0 + row) * DD + cc0 + c4);
        tile[row][c4 + 0] = v.x; tile[row][c4 + 1] = v.y;
        tile[row][c4 + 2] = v.z; tile[row][c4 + 3] = v.w;
    }
    __syncthreads();
#pragma unroll
    for (int l2 = 0; l2 < 4; l2++) {
        int fi = l2 * 256 + t;
        int c = fi >> 4, jq = (fi & 15) * 4;
        uint2 pk;
        pk.x = bf16rne(tile[jq + 0][c]) | (bf16rne(tile[jq + 1][c]) << 16);
        pk.y = bf16rne(tile[jq + 2][c]) | (bf16rne(tile[jq + 3][c]) << 16);
        *(uint2*)(WhbT + (size_t)(cc0 + c) * NN + j0 + jq) = pk;
    }
}

// ---------------- PV via MFMA: out = relu(P @ Wh) ----------------
// 512 blocks: 256 i-tiles (32 rows) x 2 c-halves (128 cols). Full K=8192 per block.
// Wave w: row-band w&1 (16 rows), col-bands (w>>1)*4 .. +4. acc = 4 x f32x4.
__global__ __launch_bounds__(256) void pv_mfma(const unsigned short* __restrict__ WhbT,
                                               const uint64_t* __restrict__ bits,
                                               const float* __restrict__ s,
                                               const float* __restrict__ dd,
                                               const float* __restrict__ Fv,
                                               const float* __restrict__ Hv,
                                               const float* __restrict__ Ep,
                                               const float* __restrict__ Gp,
                                               float* __restrict__ out) {
    __shared__ __align__(16) unsigned short fragA[2 * 64 * 8];   // 2 KB, A-frag order
    __shared__ __align__(16) unsigned short fragB[8 * 64 * 8];   // 8 KB, B-frag order
    const int t = threadIdx.x;
    const int w = t >> 6, l = t & 63;
    const int i0 = (int)(blockIdx.x >> 1) * 32;
    const int c0 = (int)(blockIdx.x & 1) * 128;

    // P-gen mapping: thread -> (band gb, frag-lane gl, half gh); 4 elems each.
    const int gb = t >> 7;
    const int gl = (t >> 1) & 63;
    const int gh = t & 1;
    const int grow = i0 + gb * 16 + (gl & 15);
    const int gk = ((gl >> 4) * 8) + gh * 4;     // k offset within 32-wide K tile
    const float si = s[grow];
    const float Epm = Ep[grow];
    const float Gpm = Gp[grow];
    const uint64_t* brow = bits + (size_t)grow * 128;

    // B staging: wave w DMAs col-bands w and w+4; lane l -> col (l&15), k-quad (l>>4).
    const unsigned short* gB0 = WhbT + (size_t)(c0 + w * 16 + (l & 15)) * NN + (l >> 4) * 8;
    const unsigned short* gB1 = gB0 + (size_t)64 * NN;

    f32x4 acc[4];
#pragma unroll
    for (int q = 0; q < 4; q++) acc[q] = (f32x4){0.f, 0.f, 0.f, 0.f};

    const int band = w & 1;
    const int cbb = (w >> 1) * 4;

    for (int jt = 0; jt < NN / 32; jt++) {
        const int j0 = jt * 32;
        __builtin_amdgcn_global_load_lds(
            (const __attribute__((address_space(1))) void*)(gB0 + j0),
            (__attribute__((address_space(3))) void*)(&fragB[w * 512]), 16, 0, 0);
        __builtin_amdgcn_global_load_lds(
            (const __attribute__((address_space(1))) void*)(gB1 + j0),
            (__attribute__((address_space(3))) void*)(&fragB[(w + 4) * 512]), 16, 0, 0);

        const int jj = j0 + gk;
        float4 d4 = *(const float4*)(dd + jj);
        float4 F4 = *(const float4*)(Fv + jj);
        float4 H4 = *(const float4*)(Hv + jj);
        uint64_t wb = brow[jj >> 6];
        int sh = jj & 63;
        float e0 = (si + d4.x >= 0.f) ? Epm * F4.x : Gpm * H4.x;
        float e1 = (si + d4.y >= 0.f) ? Epm * F4.y : Gpm * H4.y;
        float e2 = (si + d4.z >= 0.f) ? Epm * F4.z : Gpm * H4.z;
        float e3 = (si + d4.w >= 0.f) ? Epm * F4.w : Gpm * H4.w;
        e0 = ((wb >> (sh + 0)) & 1) ? e0 : 0.f;
        e1 = ((wb >> (sh + 1)) & 1) ? e1 : 0.f;
        e2 = ((wb >> (sh + 2)) & 1) ? e2 : 0.f;
        e3 = ((wb >> (sh + 3)) & 1) ? e3 : 0.f;
        uint2 pk;
        pk.x = bf16rne(e0) | (bf16rne(e1) << 16);
        pk.y = bf16rne(e2) | (bf16rne(e3) << 16);
        ((uint2*)fragA)[(gb * 64 + gl) * 2 + gh] = pk;

        __syncthreads();   // drains ds_write + global_load_lds (vmcnt0 before barrier)
        short8 af = *(const short8*)&fragA[(band * 64 + l) * 8];
#pragma unroll
        for (int q = 0; q < 4; q++) {
            short8 bf = *(const short8*)&fragB[((cbb + q) * 64 + l) * 8];
            acc[q] = __builtin_amdgcn_mfma_f32_16x16x32_bf16(af, bf, acc[q], 0, 0, 0);
        }
        __syncthreads();
    }

    // C layout (16x16x32): col = lane&15, row = (lane>>4)*4 + reg. Fused ReLU.
    const int orow = i0 + band * 16 + (l >> 4) * 4;
    const int ocol = c0 + cbb * 16 + (l & 15);
#pragma unroll
    for (int q = 0; q < 4; q++) {
#pragma unroll
        for (int r = 0; r < 4; r++) {
            out[(size_t)(orow + r) * DD + ocol + q * 16] = fmaxf(acc[q][r], 0.f);
        }
    }
}

extern "C" void kernel_launch(void* const* d_in, const int* in_sizes, int n_in,
                              void* d_out, int out_size, void* d_ws, size_t ws_size,
                              hipStream_t stream) {
    const float* x   = (const float*)d_in[0];
    const int* adj   = (const int*)d_in[1];
    const float* W1  = (const float*)d_in[2];
    const float* a1s = (const float*)d_in[3];
    const float* a1d = (const float*)d_in[4];
    const float* W2  = (const float*)d_in[5];
    const float* a2s = (const float*)d_in[6];
    const float* a2d = (const float*)d_in[7];
    float* out = (float*)d_out;

    char* ws = (char*)d_ws;
    const size_t MB = 1024ull * 1024ull;
    float*          Wh   = (float*)(ws);                       // 8 MB
    uint64_t*       bits = (uint64_t*)(ws + 8 * MB);           // 8 MB
    float*          sArr = (float*)(ws + 16 * MB);             // 8 x 32 KB:
    float*          ddA  = sArr + NN;
    float*          EpA  = sArr + 2 * NN;
    float*          GpA  = sArr + 3 * NN;
    float*          FvA  = sArr + 4 * NN;
    float*          HvA  = sArr + 5 * NN;
    unsigned short* WhbT = (unsigned short*)(ws + 17 * MB);    // 4 MB

    // ---------------- Layer 1 ----------------
    gemm_k256<<<dim3(256), dim3(256), 0, stream>>>(x, W1, Wh);
    rowdots<<<dim3(2048), dim3(256), 0, stream>>>(Wh, a1s, a1d, sArr, ddA, FvA, HvA);
    rowstats<<<dim3(NN), dim3(256), 0, stream>>>(adj, nullptr, bits, sArr, ddA, EpA, GpA, 0);
    transp_bf16<<<dim3(512), dim3(256), 0, stream>>>(Wh, WhbT);
    pv_mfma<<<dim3(512), dim3(256), 0, stream>>>(WhbT, bits, sArr, ddA, FvA, HvA, EpA, GpA, out);

    // ---------------- Layer 2 ----------------
    gemm_k256<<<dim3(256), dim3(256), 0, stream>>>(out, W2, Wh);
    rowdots<<<dim3(2048), dim3(256), 0, stream>>>(Wh, a2s, a2d, sArr, ddA, FvA, HvA);
    rowstats<<<dim3(NN), dim3(256), 0, stream>>>(nullptr, bits, nullptr, sArr, ddA, EpA, GpA, 1);
    transp_bf16<<<dim3(512), dim3(256), 0, stream>>>(Wh, WhbT);
    pv_mfma<<<dim3(512), dim3(256), 0, stream>>>(WhbT, bits, sArr, ddA, FvA, HvA, EpA, GpA, out);
}

// Round 3
// 1130.473 us; speedup vs baseline: 1.5568x; 1.1358x over previous
//
#include <hip/hip_runtime.h>
#include <cstdint>
#include <cstddef>

// GAT 2-layer (N=8192, D=256), flash softmax with rank-1 scores, bf16 MFMA PV.
// p_ij = adj_ij ? (s_i+d_j>=0 ? E'_i*F_j : G'_i*H_j) : 0   (exp-factorized softmax)
// PV: out = relu(P @ Wh). P generated in LDS in A-frag order (double-buffered);
// Wh pre-packed (in gemm epilogue) into B-fragment panels so B-frags are loaded
// global->VGPR with coalesced dwordx4, software-prefetched one K-chunk ahead.
// ws (21 MB): Wh f32 @0 (8MB) | bits @8MB (8MB) | small arrays @16MB | Bpack @17MB (4MB)

#define ALPHA 0.2f
#define NN 8192
#define DD 256

typedef __attribute__((ext_vector_type(8))) short short8;
typedef __attribute__((ext_vector_type(4))) float f32x4;

__device__ __forceinline__ unsigned bf16rne(float x) {
    union { float f; unsigned u; } c; c.f = x;
    return (c.u + 0x7fffu + ((c.u >> 16) & 1u)) >> 16;
}

// ---------------- GEMM: Wh[8192 x 256] = A @ B[256 x 256], fp32 ----------------
// Also packs Wh into Bpack bf16 MFMA-B-fragment panels:
//   Bpack[((jt*16 + ct)*64 + lane)*8 + q] = bf16(Wh[jt*32 + (lane>>4)*8 + q][ct*16 + (lane&15)])
__global__ __launch_bounds__(256) void gemm_k256(const float* __restrict__ A,
                                                 const float* __restrict__ B,
                                                 float* __restrict__ C,
                                                 unsigned short* __restrict__ Bpack) {
    __shared__ __align__(16) float At[32][36];
    __shared__ __align__(16) float4 Bs[32][64];
    const int t = threadIdx.x;
    const int m0 = blockIdx.x * 32;
    const int r0 = (t >> 5) * 4;
    const int cl = t & 31;
    float acc[4][8];
#pragma unroll
    for (int i = 0; i < 4; i++)
#pragma unroll
        for (int j = 0; j < 8; j++) acc[i][j] = 0.f;

    for (int k0 = 0; k0 < DD; k0 += 32) {
        {
            int row = t >> 3, kq = t & 7;
            float4 v = *(const float4*)(A + (size_t)(m0 + row) * DD + k0 + kq * 4);
            At[kq * 4 + 0][row] = v.x; At[kq * 4 + 1][row] = v.y;
            At[kq * 4 + 2][row] = v.z; At[kq * 4 + 3][row] = v.w;
        }
#pragma unroll
        for (int l2 = 0; l2 < 8; l2++) {
            int fi = l2 * 256 + t;
            Bs[fi >> 6][fi & 63] =
                *(const float4*)(B + (size_t)(k0 + (fi >> 6)) * DD + (fi & 63) * 4);
        }
        __syncthreads();
#pragma unroll
        for (int k = 0; k < 32; k++) {
            float4 a0 = *(const float4*)&At[k][r0];
            float4 b0 = Bs[k][cl], b1 = Bs[k][cl + 32];
            float av[4] = {a0.x, a0.y, a0.z, a0.w};
            float bv[8] = {b0.x, b0.y, b0.z, b0.w, b1.x, b1.y, b1.z, b1.w};
#pragma unroll
            for (int i = 0; i < 4; i++)
#pragma unroll
                for (int j = 0; j < 8; j++) acc[i][j] += av[i] * bv[j];
        }
        __syncthreads();
    }
    // fp32 Wh stores
#pragma unroll
    for (int i = 0; i < 4; i++) {
        float4 v0 = {acc[i][0], acc[i][1], acc[i][2], acc[i][3]};
        float4 v1 = {acc[i][4], acc[i][5], acc[i][6], acc[i][7]};
        *(float4*)(C + (size_t)(m0 + r0 + i) * DD + cl * 4) = v0;
        *(float4*)(C + (size_t)(m0 + r0 + i) * DD + 128 + cl * 4) = v1;
    }
    // Bpack bf16 stores: nodes j = m0+r0+0..3 (one 8-group), 8 feature cols
    const int jt = m0 >> 5;
    const int lq = ((r0 >> 3) & 3) * 16;   // (j>>3)&3 part of lane
    const int i8 = r0 & 4;                 // idx within 8-group
#pragma unroll
    for (int h = 0; h < 2; h++) {
#pragma unroll
        for (int cc = 0; cc < 4; cc++) {
            int c = h * 128 + cl * 4 + cc;
            int ct = c >> 4;
            int lane = lq + (c & 15);
            uint2 pk;
            pk.x = bf16rne(acc[0][h * 4 + cc]) | (bf16rne(acc[1][h * 4 + cc]) << 16);
            pk.y = bf16rne(acc[2][h * 4 + cc]) | (bf16rne(acc[3][h * 4 + cc]) << 16);
            *(uint2*)(Bpack + ((size_t)(jt * 16 + ct) * 64 + lane) * 8 + i8) = pk;
        }
    }
}

// ------- s[i]=Wh[i].a_src; d[i]=Wh[i].a_dst; F=exp(d); H=exp(a*d) (1 wave/row) -------
__global__ __launch_bounds__(256) void rowdots(const float* __restrict__ Wh,
                                               const float* __restrict__ a_src,
                                               const float* __restrict__ a_dst,
                                               float* __restrict__ s,
                                               float* __restrict__ dd,
                                               float* __restrict__ Fv,
                                               float* __restrict__ Hv) {
    int wave = threadIdx.x >> 6;
    int lane = threadIdx.x & 63;
    int row = blockIdx.x * 4 + wave;
    float4 w = *(const float4*)(Wh + (size_t)row * DD + lane * 4);
    float4 as = *(const float4*)(a_src + lane * 4);
    float4 ad = *(const float4*)(a_dst + lane * 4);
    float ss = w.x * as.x + w.y * as.y + w.z * as.z + w.w * as.w;
    float sd = w.x * ad.x + w.y * ad.y + w.z * ad.z + w.w * ad.w;
#pragma unroll
    for (int off = 32; off; off >>= 1) {
        ss += __shfl_down(ss, off);
        sd += __shfl_down(sd, off);
    }
    if (lane == 0) {
        s[row] = ss; dd[row] = sd;
        Fv[row] = __expf(sd); Hv[row] = __expf(ALPHA * sd);
    }
}

// ------ per-row m, rl=1/l; E'=rl*exp(s-m), G'=rl*exp(a*s-m); packs bitmask (mode 0) ------
__global__ __launch_bounds__(256) void rowstats(const int* __restrict__ adj,
                                                const uint64_t* __restrict__ bits_in,
                                                uint64_t* __restrict__ bits_out,
                                                const float* __restrict__ s,
                                                const float* __restrict__ dd,
                                                float* __restrict__ Ep,
                                                float* __restrict__ Gp,
                                                int mode) {
    __shared__ uint64_t masks[128];
    __shared__ float wmax[4];
    __shared__ float wsum[4];
    const int i = blockIdx.x;
    const int t = threadIdx.x;
    const int wave = t >> 6, lane = t & 63;
    const float si = s[i];
    float mx = -3.0e38f;

    if (mode == 0) {
        for (int it = 0; it < 32; it++) {
            int j = it * 256 + t;
            int a = adj[(size_t)i * NN + j];
            unsigned long long mk = __ballot(a != 0);
            if (lane == 0) masks[it * 4 + wave] = mk;
            if (a != 0) {
                float e = si + dd[j];
                e = e >= 0.f ? e : ALPHA * e;
                mx = fmaxf(mx, e);
            }
        }
    } else {
        for (int it = 0; it < 32; it++) {
            int j = it * 256 + t;
            int widx = it * 4 + wave;
            uint64_t mk = bits_in[(size_t)i * 128 + widx];
            if (lane == 0) masks[widx] = mk;
            if ((mk >> lane) & 1ull) {
                float e = si + dd[j];
                e = e >= 0.f ? e : ALPHA * e;
                mx = fmaxf(mx, e);
            }
        }
    }
#pragma unroll
    for (int off = 32; off; off >>= 1) mx = fmaxf(mx, __shfl_down(mx, off));
    if (lane == 0) wmax[wave] = mx;
    __syncthreads();
    const float mrow = fmaxf(fmaxf(wmax[0], wmax[1]), fmaxf(wmax[2], wmax[3]));

    float sm = 0.f;
    for (int it = 0; it < 32; it++) {
        int j = it * 256 + t;
        uint64_t mk = masks[it * 4 + wave];
        if ((mk >> lane) & 1ull) {
            float e = si + dd[j];
            e = e >= 0.f ? e : ALPHA * e;
            sm += __expf(e - mrow);
        }
    }
#pragma unroll
    for (int off = 32; off; off >>= 1) sm += __shfl_down(sm, off);
    if (lane == 0) wsum[wave] = sm;
    __syncthreads();
    if (t == 0) {
        float rl = 1.0f / (wsum[0] + wsum[1] + wsum[2] + wsum[3]);
        Ep[i] = rl * __expf(si - mrow);
        Gp[i] = rl * __expf(ALPHA * si - mrow);
    }
    if (mode == 0) {
        if (t < 128) bits_out[(size_t)i * 128 + t] = masks[t];
    }
}

// ---------------- PV via MFMA: out = relu(P @ Wh) ----------------
// 256 blocks x 512 thr: 128 i-tiles (64 rows) x 2 col-halves (128 cols), K=8192.
// Wave w: row bands {2*(w&1), 2*(w&1)+1}, col tiles {2*(w>>1), 2*(w>>1)+1} (block-local).
// A (P) generated into LDS A-frag order, double-buffered; B-frags prefetched to VGPRs.
__global__ __launch_bounds__(512) void pv_mfma(const unsigned short* __restrict__ Bpack,
                                               const uint64_t* __restrict__ bits,
                                               const float* __restrict__ s,
                                               const float* __restrict__ dd,
                                               const float* __restrict__ Fv,
                                               const float* __restrict__ Hv,
                                               const float* __restrict__ Ep,
                                               const float* __restrict__ Gp,
                                               float* __restrict__ out) {
    __shared__ __align__(16) unsigned short fragA[2][4 * 64 * 8];   // [buf][(band*64+l)*8]
    const int t = threadIdx.x;
    const int w = t >> 6, l = t & 63;
    const int i0 = (int)(blockIdx.x >> 1) * 64;
    const int ct0 = (int)(blockIdx.x & 1) * 8;       // global col-tile base

    // P-gen mapping: 4 P values per thread per chunk (one uint2 in frag order)
    const int gb = t >> 7;                 // band 0..3
    const int gl = (t >> 1) & 63;          // frag lane
    const int gh = t & 1;                  // k-half-of-8
    const int grow = i0 + gb * 16 + (gl & 15);
    const int gk = (gl >> 4) * 8 + gh * 4; // k offset in 32-wide chunk
    const float si = s[grow];
    const float Epm = Ep[grow];
    const float Gpm = Gp[grow];
    const uint64_t* brow = bits + (size_t)grow * 128;

    // wave tile mapping
    const int rb = w & 1;                  // bands 2rb, 2rb+1
    const int tq = w >> 1;                 // block-local tiles 2tq, 2tq+1
    const unsigned short* bbase = Bpack + ((size_t)(ct0 + tq * 2) * 64 + l) * 8;

    f32x4 acc[2][2];
#pragma unroll
    for (int i = 0; i < 2; i++)
#pragma unroll
        for (int q = 0; q < 2; q++) acc[i][q] = (f32x4){0.f, 0.f, 0.f, 0.f};

    // ---- P-gen for chunk jt into fragA[nbuf] ----
    auto gen = [&](int jt, int nbuf) {
        const int jj = jt * 32 + gk;
        float4 d4 = *(const float4*)(dd + jj);
        float4 F4 = *(const float4*)(Fv + jj);
        float4 H4 = *(const float4*)(Hv + jj);
        uint64_t wb = brow[jj >> 6];
        int sh = jj & 63;
        float e0 = (si + d4.x >= 0.f) ? Epm * F4.x : Gpm * H4.x;
        float e1 = (si + d4.y >= 0.f) ? Epm * F4.y : Gpm * H4.y;
        float e2 = (si + d4.z >= 0.f) ? Epm * F4.z : Gpm * H4.z;
        float e3 = (si + d4.w >= 0.f) ? Epm * F4.w : Gpm * H4.w;
        e0 = ((wb >> (sh + 0)) & 1) ? e0 : 0.f;
        e1 = ((wb >> (sh + 1)) & 1) ? e1 : 0.f;
        e2 = ((wb >> (sh + 2)) & 1) ? e2 : 0.f;
        e3 = ((wb >> (sh + 3)) & 1) ? e3 : 0.f;
        uint2 pk;
        pk.x = bf16rne(e0) | (bf16rne(e1) << 16);
        pk.y = bf16rne(e2) | (bf16rne(e3) << 16);
        ((uint2*)&fragA[nbuf][0])[(gb * 64 + gl) * 2 + gh] = pk;
    };

    // ---- prologue: chunk 0 ----
    gen(0, 0);
    short8 Bcur0 = *(const short8*)(bbase + (size_t)0 * 16 * 512);
    short8 Bcur1 = *(const short8*)(bbase + 512 + (size_t)0 * 16 * 512);
    __syncthreads();

    for (int jt = 0; jt < NN / 32; jt++) {
        const int buf = jt & 1;
        const int jn = (jt + 1) & (NN / 32 - 1);
        // prefetch B(jt+1) -> regs (in flight across this iteration)
        const unsigned short* bp = bbase + (size_t)jn * 16 * 512;
        short8 Bn0 = *(const short8*)(bp);
        short8 Bn1 = *(const short8*)(bp + 512);
        // generate P(jt+1) -> other LDS buffer
        gen(jn, buf ^ 1);
        // A-frags for this chunk
        short8 a0 = *(const short8*)&fragA[buf][((2 * rb) * 64 + l) * 8];
        short8 a1 = *(const short8*)&fragA[buf][((2 * rb + 1) * 64 + l) * 8];
        acc[0][0] = __builtin_amdgcn_mfma_f32_16x16x32_bf16(a0, Bcur0, acc[0][0], 0, 0, 0);
        acc[0][1] = __builtin_amdgcn_mfma_f32_16x16x32_bf16(a0, Bcur1, acc[0][1], 0, 0, 0);
        acc[1][0] = __builtin_amdgcn_mfma_f32_16x16x32_bf16(a1, Bcur0, acc[1][0], 0, 0, 0);
        acc[1][1] = __builtin_amdgcn_mfma_f32_16x16x32_bf16(a1, Bcur1, acc[1][1], 0, 0, 0);
        __syncthreads();
        Bcur0 = Bn0; Bcur1 = Bn1;
    }

    // C layout: col = l&15, row = (l>>4)*4 + r. Fused ReLU, direct store.
#pragma unroll
    for (int i2 = 0; i2 < 2; i2++) {
        const int orow = i0 + (2 * rb + i2) * 16 + (l >> 4) * 4;
#pragma unroll
        for (int q = 0; q < 2; q++) {
            const int ocol = (ct0 + 2 * tq + q) * 16 + (l & 15);
#pragma unroll
            for (int r = 0; r < 4; r++) {
                out[(size_t)(orow + r) * DD + ocol] = fmaxf(acc[i2][q][r], 0.f);
            }
        }
    }
}

extern "C" void kernel_launch(void* const* d_in, const int* in_sizes, int n_in,
                              void* d_out, int out_size, void* d_ws, size_t ws_size,
                              hipStream_t stream) {
    const float* x   = (const float*)d_in[0];
    const int* adj   = (const int*)d_in[1];
    const float* W1  = (const float*)d_in[2];
    const float* a1s = (const float*)d_in[3];
    const float* a1d = (const float*)d_in[4];
    const float* W2  = (const float*)d_in[5];
    const float* a2s = (const float*)d_in[6];
    const float* a2d = (const float*)d_in[7];
    float* out = (float*)d_out;

    char* ws = (char*)d_ws;
    const size_t MB = 1024ull * 1024ull;
    float*          Wh    = (float*)(ws);                    // 8 MB
    uint64_t*       bits  = (uint64_t*)(ws + 8 * MB);        // 8 MB
    float*          sArr  = (float*)(ws + 16 * MB);          // 6 x 32 KB
    float*          ddA   = sArr + NN;
    float*          EpA   = sArr + 2 * NN;
    float*          GpA   = sArr + 3 * NN;
    float*          FvA   = sArr + 4 * NN;
    float*          HvA   = sArr + 5 * NN;
    unsigned short* Bpack = (unsigned short*)(ws + 17 * MB); // 4 MB

    // ---------------- Layer 1 ----------------
    gemm_k256<<<dim3(256), dim3(256), 0, stream>>>(x, W1, Wh, Bpack);
    rowdots<<<dim3(2048), dim3(256), 0, stream>>>(Wh, a1s, a1d, sArr, ddA, FvA, HvA);
    rowstats<<<dim3(NN), dim3(256), 0, stream>>>(adj, nullptr, bits, sArr, ddA, EpA, GpA, 0);
    pv_mfma<<<dim3(256), dim3(512), 0, stream>>>(Bpack, bits, sArr, ddA, FvA, HvA, EpA, GpA, out);

    // ---------------- Layer 2 ----------------
    gemm_k256<<<dim3(256), dim3(256), 0, stream>>>(out, W2, Wh, Bpack);
    rowdots<<<dim3(2048), dim3(256), 0, stream>>>(Wh, a2s, a2d, sArr, ddA, FvA, HvA);
    rowstats<<<dim3(NN), dim3(256), 0, stream>>>(nullptr, bits, nullptr, sArr, ddA, EpA, GpA, 1);
    pv_mfma<<<dim3(256), dim3(512), 0, stream>>>(Bpack, bits, sArr, ddA, FvA, HvA, EpA, GpA, out);
}

// Round 4
// 928.582 us; speedup vs baseline: 1.8953x; 1.2174x over previous
//
#include <hip/hip_runtime.h>
#include <cstdint>
#include <cstddef>

// GAT 2-layer (N=8192, D=256), flash softmax with rank-1 scores, bf16 MFMA PV.
// p_ij = adj_ij ? max(E'_i*F_j, G'_i*H_j) : 0   (leaky commutes with exp under max)
//   E'=rl*exp(s-m), G'=rl*exp(a*s-m) per row;  F=exp(d), H=exp(a*d) per col (FH interleaved)
// pv: 512 blocks (128 i-tiles x 4 col-quarters) x 512 thr; intra-block K-split x2
// (waves 0-3 = K-half 0, waves 4-7 = K-half 1; LDS reduction at end). P generated
// into LDS A-frag order (dbuf); B-frags (pre-packed in gemm epilogue) prefetched to
// VGPRs across the barrier (no vmcnt(0) drain for reg-destined loads).
// ws (21 MB): Wh f32 @0 (8MB) | bits @8MB (8MB) | small arrays @16MB | Bpack @17MB (4MB)

#define ALPHA 0.2f
#define NN 8192
#define DD 256

typedef __attribute__((ext_vector_type(8))) short short8;
typedef __attribute__((ext_vector_type(4))) float f32x4;

__device__ __forceinline__ unsigned bf16rne(float x) {
    union { float f; unsigned u; } c; c.f = x;
    return (c.u + 0x7fffu + ((c.u >> 16) & 1u)) >> 16;
}

#if __has_builtin(__builtin_amdgcn_cvt_pk_bf16_f32)
__device__ __forceinline__ unsigned pk_bf16(float a, float b) {
    return __builtin_bit_cast(unsigned, __builtin_amdgcn_cvt_pk_bf16_f32(a, b));
}
#else
__device__ __forceinline__ unsigned pk_bf16(float a, float b) {
    return bf16rne(a) | (bf16rne(b) << 16);
}
#endif

// ---------------- GEMM: Wh[8192 x 256] = A @ B[256 x 256], fp32 ----------------
// 512 blocks: 256 row-tiles (32) x 2 col-halves (128). Packs Wh into Bpack bf16
// MFMA-B panels: Bpack[((jt*16+ct)*64+lane)*8+q] = bf16(Wh[jt*32+(lane>>4)*8+q][ct*16+(lane&15)])
__global__ __launch_bounds__(256) void gemm_k256(const float* __restrict__ A,
                                                 const float* __restrict__ B,
                                                 float* __restrict__ C,
                                                 unsigned short* __restrict__ Bpack) {
    __shared__ __align__(16) float At[32][36];
    __shared__ __align__(16) float4 Bs[32][32];
    const int t = threadIdx.x;
    const int m0 = (int)(blockIdx.x >> 1) * 32;
    const int half = blockIdx.x & 1;
    const int r0 = (t >> 5) * 4;
    const int cl = t & 31;
    float acc[4][4];
#pragma unroll
    for (int i = 0; i < 4; i++)
#pragma unroll
        for (int j = 0; j < 4; j++) acc[i][j] = 0.f;

    for (int k0 = 0; k0 < DD; k0 += 32) {
        {
            int row = t >> 3, kq = t & 7;
            float4 v = *(const float4*)(A + (size_t)(m0 + row) * DD + k0 + kq * 4);
            At[kq * 4 + 0][row] = v.x; At[kq * 4 + 1][row] = v.y;
            At[kq * 4 + 2][row] = v.z; At[kq * 4 + 3][row] = v.w;
        }
#pragma unroll
        for (int l2 = 0; l2 < 4; l2++) {
            int fi = l2 * 256 + t;
            Bs[fi >> 5][fi & 31] =
                *(const float4*)(B + (size_t)(k0 + (fi >> 5)) * DD + half * 128 + (fi & 31) * 4);
        }
        __syncthreads();
#pragma unroll
        for (int k = 0; k < 32; k++) {
            float4 a0 = *(const float4*)&At[k][r0];
            float4 b0 = Bs[k][cl];
            float av[4] = {a0.x, a0.y, a0.z, a0.w};
            float bv[4] = {b0.x, b0.y, b0.z, b0.w};
#pragma unroll
            for (int i = 0; i < 4; i++)
#pragma unroll
                for (int j = 0; j < 4; j++) acc[i][j] += av[i] * bv[j];
        }
        __syncthreads();
    }
#pragma unroll
    for (int i = 0; i < 4; i++) {
        float4 v0 = {acc[i][0], acc[i][1], acc[i][2], acc[i][3]};
        *(float4*)(C + (size_t)(m0 + r0 + i) * DD + half * 128 + cl * 4) = v0;
    }
    const int jt = m0 >> 5;
    const int lq = ((r0 >> 3) & 3) * 16;
    const int i8 = r0 & 4;
#pragma unroll
    for (int cc = 0; cc < 4; cc++) {
        int c = half * 128 + cl * 4 + cc;
        int ct = c >> 4;
        int lane = lq + (c & 15);
        uint2 pk;
        pk.x = pk_bf16(acc[0][cc], acc[1][cc]);
        pk.y = pk_bf16(acc[2][cc], acc[3][cc]);
        *(uint2*)(Bpack + ((size_t)(jt * 16 + ct) * 64 + lane) * 8 + i8) = pk;
    }
}

// ------- s,d row dots; FH[2i]=exp(d), FH[2i+1]=exp(a*d) (1 wave/row) -------
__global__ __launch_bounds__(256) void rowdots(const float* __restrict__ Wh,
                                               const float* __restrict__ a_src,
                                               const float* __restrict__ a_dst,
                                               float* __restrict__ s,
                                               float* __restrict__ dd,
                                               float* __restrict__ FH) {
    int wave = threadIdx.x >> 6;
    int lane = threadIdx.x & 63;
    int row = blockIdx.x * 4 + wave;
    float4 w = *(const float4*)(Wh + (size_t)row * DD + lane * 4);
    float4 as = *(const float4*)(a_src + lane * 4);
    float4 ad = *(const float4*)(a_dst + lane * 4);
    float ss = w.x * as.x + w.y * as.y + w.z * as.z + w.w * as.w;
    float sd = w.x * ad.x + w.y * ad.y + w.z * ad.z + w.w * ad.w;
#pragma unroll
    for (int off = 32; off; off >>= 1) {
        ss += __shfl_down(ss, off);
        sd += __shfl_down(sd, off);
    }
    if (lane == 0) {
        s[row] = ss; dd[row] = sd;
        FH[2 * row] = __expf(sd);
        FH[2 * row + 1] = __expf(ALPHA * sd);
    }
}

// ------ per-row m, rl=1/l; E'=rl*exp(s-m), G'=rl*exp(a*s-m); packs bitmask (mode 0) ------
__global__ __launch_bounds__(256) void rowstats(const int* __restrict__ adj,
                                                const uint64_t* __restrict__ bits_in,
                                                uint64_t* __restrict__ bits_out,
                                                const float* __restrict__ s,
                                                const float* __restrict__ dd,
                                                float* __restrict__ Ep,
                                                float* __restrict__ Gp,
                                                int mode) {
    __shared__ uint64_t masks[128];
    __shared__ float wmax[4];
    __shared__ float wsum[4];
    const int i = blockIdx.x;
    const int t = threadIdx.x;
    const int wave = t >> 6, lane = t & 63;
    const float si = s[i];
    float mx = -3.0e38f;

    if (mode == 0) {
        for (int it = 0; it < 32; it++) {
            int j = it * 256 + t;
            int a = adj[(size_t)i * NN + j];
            unsigned long long mk = __ballot(a != 0);
            if (lane == 0) masks[it * 4 + wave] = mk;
            if (a != 0) {
                float e = si + dd[j];
                e = e >= 0.f ? e : ALPHA * e;
                mx = fmaxf(mx, e);
            }
        }
    } else {
        for (int it = 0; it < 32; it++) {
            int j = it * 256 + t;
            int widx = it * 4 + wave;
            uint64_t mk = bits_in[(size_t)i * 128 + widx];
            if (lane == 0) masks[widx] = mk;
            if ((mk >> lane) & 1ull) {
                float e = si + dd[j];
                e = e >= 0.f ? e : ALPHA * e;
                mx = fmaxf(mx, e);
            }
        }
    }
#pragma unroll
    for (int off = 32; off; off >>= 1) mx = fmaxf(mx, __shfl_down(mx, off));
    if (lane == 0) wmax[wave] = mx;
    __syncthreads();
    const float mrow = fmaxf(fmaxf(wmax[0], wmax[1]), fmaxf(wmax[2], wmax[3]));

    float sm = 0.f;
    for (int it = 0; it < 32; it++) {
        int j = it * 256 + t;
        uint64_t mk = masks[it * 4 + wave];
        if ((mk >> lane) & 1ull) {
            float e = si + dd[j];
            e = e >= 0.f ? e : ALPHA * e;
            sm += __expf(e - mrow);
        }
    }
#pragma unroll
    for (int off = 32; off; off >>= 1) sm += __shfl_down(sm, off);
    if (lane == 0) wsum[wave] = sm;
    __syncthreads();
    if (t == 0) {
        float rl = 1.0f / (wsum[0] + wsum[1] + wsum[2] + wsum[3]);
        Ep[i] = rl * __expf(si - mrow);
        Gp[i] = rl * __expf(ALPHA * si - mrow);
    }
    if (mode == 0) {
        if (t < 128) bits_out[(size_t)i * 128 + t] = masks[t];
    }
}

// ---------------- PV via MFMA: out = relu(P @ Wh) ----------------
// 512 blocks x 512 thr: (i-tile = bx>>2, 64 rows) x (col-quarter = bx&3, 64 cols).
// Waves: kh = w>>2 (K half, 128 chunks each), sub = w&3: rb = sub&1 (row bands
// 2rb,2rb+1), tq = sub>>1 (col tiles 2tq,2tq+1). 4 MFMA/wave/chunk.
// End: kh=1 partials -> LDS -> kh=0 adds, relu, stores.
__global__ __launch_bounds__(512, 6) void pv_mfma(const unsigned short* __restrict__ Bpack,
                                                  const uint64_t* __restrict__ bits,
                                                  const float* __restrict__ FH,
                                                  const float* __restrict__ Ep,
                                                  const float* __restrict__ Gp,
                                                  float* __restrict__ out) {
    __shared__ __align__(16) unsigned short fragA[2][2][2048];   // [kh][buf], 16 KB
    const int t = threadIdx.x;
    const int w = t >> 6, l = t & 63;
    const int i0 = (int)(blockIdx.x >> 2) * 64;
    const int ct0 = (int)(blockIdx.x & 3) * 4;      // global col-tile base (4 tiles)
    const int kh = w >> 2;
    const int sub = w & 3;
    const int rb = sub & 1;
    const int tq = sub >> 1;
    const int cbase = kh * 128;                     // K-chunk base for this half

    // P-gen: 256 threads per kh half; each fills 2 slots (8 elems) per chunk.
    const int u = t & 255;
    int gkE[2], slotE[2];
    float EpE[2], GpE[2];
    const uint64_t* browE[2];
#pragma unroll
    for (int e = 0; e < 2; e++) {
        int s_ = u + e * 256;                       // slot index 0..511
        int gb = s_ >> 7, gl = (s_ >> 1) & 63, gh = s_ & 1;
        int grow = i0 + gb * 16 + (gl & 15);
        gkE[e] = (gl >> 4) * 8 + gh * 4;
        slotE[e] = s_;
        EpE[e] = Ep[grow];
        GpE[e] = Gp[grow];
        browE[e] = bits + (size_t)grow * 128;
    }

    auto gen = [&](int chunk, int nbuf) {
        uint2* dst = (uint2*)&fragA[kh][nbuf][0];
#pragma unroll
        for (int e = 0; e < 2; e++) {
            int jj = chunk * 32 + gkE[e];
            float4 fh0 = *(const float4*)(FH + 2 * jj);
            float4 fh1 = *(const float4*)(FH + 2 * jj + 4);
            uint32_t wl = (uint32_t)(browE[e][chunk >> 1] >> (((chunk & 1) << 5) + gkE[e]));
            float p0 = fmaxf(EpE[e] * fh0.x, GpE[e] * fh0.y);
            float p1 = fmaxf(EpE[e] * fh0.z, GpE[e] * fh0.w);
            float p2 = fmaxf(EpE[e] * fh1.x, GpE[e] * fh1.y);
            float p3 = fmaxf(EpE[e] * fh1.z, GpE[e] * fh1.w);
            p0 = (wl & 1u) ? p0 : 0.f;
            p1 = (wl & 2u) ? p1 : 0.f;
            p2 = (wl & 4u) ? p2 : 0.f;
            p3 = (wl & 8u) ? p3 : 0.f;
            uint2 pk;
            pk.x = pk_bf16(p0, p1);
            pk.y = pk_bf16(p2, p3);
            dst[slotE[e]] = pk;
        }
    };

    const unsigned short* bb = Bpack + ((size_t)(ct0 + 2 * tq) * 64 + l) * 8;

    f32x4 acc[2][2];
#pragma unroll
    for (int i = 0; i < 2; i++)
#pragma unroll
        for (int q = 0; q < 2; q++) acc[i][q] = (f32x4){0.f, 0.f, 0.f, 0.f};

    gen(cbase, 0);
    short8 Bc0, Bc1;
    {
        const unsigned short* bp = bb + (size_t)cbase * 8192;
        Bc0 = *(const short8*)bp;
        Bc1 = *(const short8*)(bp + 512);
    }
    __syncthreads();

    for (int jl = 0; jl < 128; jl++) {
        const int buf = jl & 1;
        const int cn = cbase + ((jl + 1) & 127);
        // prefetch next B -> VGPRs (stays in flight across the barrier)
        const unsigned short* bp = bb + (size_t)cn * 8192;
        short8 Bn0 = *(const short8*)bp;
        short8 Bn1 = *(const short8*)(bp + 512);
        // generate next P tile into the other LDS buffer
        gen(cn, buf ^ 1);
        // consume current chunk
        const unsigned short* fA = &fragA[kh][buf][(2 * rb * 64 + l) * 8];
        short8 a0 = *(const short8*)fA;
        short8 a1 = *(const short8*)(fA + 512);
        acc[0][0] = __builtin_amdgcn_mfma_f32_16x16x32_bf16(a0, Bc0, acc[0][0], 0, 0, 0);
        acc[0][1] = __builtin_amdgcn_mfma_f32_16x16x32_bf16(a0, Bc1, acc[0][1], 0, 0, 0);
        acc[1][0] = __builtin_amdgcn_mfma_f32_16x16x32_bf16(a1, Bc0, acc[1][0], 0, 0, 0);
        acc[1][1] = __builtin_amdgcn_mfma_f32_16x16x32_bf16(a1, Bc1, acc[1][1], 0, 0, 0);
        __syncthreads();
        Bc0 = Bn0; Bc1 = Bn1;
    }

    // cross-kh reduction in LDS (reuse fragA: 4096 floats), then relu + store.
    __syncthreads();
    float* red = (float*)&fragA[0][0][0];
    const int rbase = (sub * 64 + l) * 16;
    if (kh == 1) {
#pragma unroll
        for (int i2 = 0; i2 < 2; i2++)
#pragma unroll
            for (int q = 0; q < 2; q++)
                *(f32x4*)&red[rbase + i2 * 8 + q * 4] = acc[i2][q];
    }
    __syncthreads();
    if (kh == 0) {
#pragma unroll
        for (int i2 = 0; i2 < 2; i2++) {
            const int orow = i0 + (2 * rb + i2) * 16 + (l >> 4) * 4;
#pragma unroll
            for (int q = 0; q < 2; q++) {
                const int ocol = (ct0 + 2 * tq + q) * 16 + (l & 15);
                f32x4 o = *(const f32x4*)&red[rbase + i2 * 8 + q * 4];
#pragma unroll
                for (int r = 0; r < 4; r++)
                    out[(size_t)(orow + r) * DD + ocol] = fmaxf(acc[i2][q][r] + o[r], 0.f);
            }
        }
    }
}

extern "C" void kernel_launch(void* const* d_in, const int* in_sizes, int n_in,
                              void* d_out, int out_size, void* d_ws, size_t ws_size,
                              hipStream_t stream) {
    const float* x   = (const float*)d_in[0];
    const int* adj   = (const int*)d_in[1];
    const float* W1  = (const float*)d_in[2];
    const float* a1s = (const float*)d_in[3];
    const float* a1d = (const float*)d_in[4];
    const float* W2  = (const float*)d_in[5];
    const float* a2s = (const float*)d_in[6];
    const float* a2d = (const float*)d_in[7];
    float* out = (float*)d_out;

    char* ws = (char*)d_ws;
    const size_t MB = 1024ull * 1024ull;
    float*          Wh    = (float*)(ws);                    // 8 MB
    uint64_t*       bits  = (uint64_t*)(ws + 8 * MB);        // 8 MB
    float*          sArr  = (float*)(ws + 16 * MB);          // small arrays
    float*          ddA   = sArr + NN;
    float*          EpA   = sArr + 2 * NN;
    float*          GpA   = sArr + 3 * NN;
    float*          FHA   = sArr + 4 * NN;                   // 2*NN floats
    unsigned short* Bpack = (unsigned short*)(ws + 17 * MB); // 4 MB

    // ---------------- Layer 1 ----------------
    gemm_k256<<<dim3(512), dim3(256), 0, stream>>>(x, W1, Wh, Bpack);
    rowdots<<<dim3(2048), dim3(256), 0, stream>>>(Wh, a1s, a1d, sArr, ddA, FHA);
    rowstats<<<dim3(NN), dim3(256), 0, stream>>>(adj, nullptr, bits, sArr, ddA, EpA, GpA, 0);
    pv_mfma<<<dim3(512), dim3(512), 0, stream>>>(Bpack, bits, FHA, EpA, GpA, out);

    // ---------------- Layer 2 ----------------
    gemm_k256<<<dim3(512), dim3(256), 0, stream>>>(out, W2, Wh, Bpack);
    rowdots<<<dim3(2048), dim3(256), 0, stream>>>(Wh, a2s, a2d, sArr, ddA, FHA);
    rowstats<<<dim3(NN), dim3(256), 0, stream>>>(nullptr, bits, nullptr, sArr, ddA, EpA, GpA, 1);
    pv_mfma<<<dim3(512), dim3(512), 0, stream>>>(Bpack, bits, FHA, EpA, GpA, out);
}